// Round 8
// baseline (201.953 us; speedup 1.0000x reference)
//
#include <hip/hip_runtime.h>
#include <hip/hip_bf16.h>

// 3x3 conv pad=1 stride=1, NHWC fp32 -> bf16 MFMA implicit GEMM.
//   M = 32*56*56 = 100352, N = 256, K = 9*128 = 1152
// R12: two-pass pipelined fused-pack prologue.  R11 fused pack_input into
// the GEMM (fixed cost -23us) but conv regressed +21us: the prologue's
// per-chunk {load fp32 -> cvt -> ds_write} chain makes each ds_write depend
// on its own loads, so the compiler emits a wait per iteration ->  ~11
// serialized HBM round-trips.  R12 issues ALL 22 float4 loads first (named
// register arrays, static indexing, full unroll -- ~88 transient VGPR; LDS
// already caps occupancy at 8 waves/CU so VGPR<=256 is free), then issues
// the 3 B-region DMAs, then converts+writes as loads retire: one round-trip.
// vmcnt ledger unchanged from the refcheck-passed R10/R11 loop: all A-loads
// are register-consumed before VMWAIT(2), which then sees only the 6 B DMAs
// outstanding (drains B0,B1, leaves B2).  Loop/swizzles/epilogue verbatim.

#define NIMG 32
#define HH 56
#define WW 56
#define CIN 128
#define COUT 256
#define KTOT 1152

#define BM 224
#define NPHASE 36                        // kh phases (K=32 each)
#define NBLK ((NIMG * HH * WW) / BM)     // 448 = 8 * 56

// LDS (shorts): A window 5632 chunks x 8 = 45056 (6x58 cells x 256 B,
// chunk = cell*16 + phys, phys = logical ^ (iw&15); 64-chunk slack);
// B: 3 regions x 8192 (256 rows x 32 k).  Total 69632 shorts = 136 KiB.
#define B_BASE 45056
#define BREG_SZ 8192
#define AWIN_CHUNKS 5568                 // real window; slack to 5632 (11x512)

typedef __attribute__((ext_vector_type(8))) short bf16x8;
typedef __attribute__((ext_vector_type(4))) short s16x4;
typedef __attribute__((ext_vector_type(4))) float f32x4;

__device__ __forceinline__ short f2bf(float x) {
    union { __hip_bfloat16 b; short s; } u;
    u.b = __float2bfloat16(x);
    return u.s;
}

typedef const void __attribute__((address_space(1)))* gas1_t;
typedef void __attribute__((address_space(3)))* las3_t;
__device__ __forceinline__ void async16(short* lds_p, const short* g) {
    __builtin_amdgcn_global_load_lds((gas1_t)g, (las3_t)lds_p, 16, 0, 0);
}

// ---- pack: weights (K=1152, N=256) fp32 -> bf16 transposed [n][k] ----------
__global__ __launch_bounds__(256) void pack_wgt(const float* __restrict__ w,
                                                short* __restrict__ wt) {
    __shared__ short tile[32][33];
    const int k0 = blockIdx.x * 32;
    const int n0 = blockIdx.y * 32;
    const int t  = threadIdx.x;
    {
        const int kl  = t >> 3;
        const int nl4 = (t & 7) * 4;
        const float4 x = *(const float4*)(w + (size_t)(k0 + kl) * COUT + n0 + nl4);
        tile[kl][nl4 + 0] = f2bf(x.x);
        tile[kl][nl4 + 1] = f2bf(x.y);
        tile[kl][nl4 + 2] = f2bf(x.z);
        tile[kl][nl4 + 3] = f2bf(x.w);
    }
    __syncthreads();
    {
        const int nl  = t >> 3;
        const int kl4 = (t & 7) * 4;
        s16x4 v;
        v.x = tile[kl4 + 0][nl];
        v.y = tile[kl4 + 1][nl];
        v.z = tile[kl4 + 2][nl];
        v.w = tile[kl4 + 3][nl];
        *(s16x4*)(wt + (size_t)(n0 + nl) * KTOT + k0 + kl4) = v;
    }
}

// ---- GEMM: 224x256 tile, fused-pack persistent-A, B-only phase staging -----
#define FENCE() asm volatile("" ::: "memory")
#define BARRIER() do { FENCE(); __builtin_amdgcn_s_barrier(); FENCE(); } while (0)
#define VMWAIT(N) asm volatile("s_waitcnt vmcnt(" #N ")" ::: "memory")
#define LGKMWAIT0() asm volatile("s_waitcnt lgkmcnt(0)" ::: "memory")

__global__ __launch_bounds__(512, 2) void conv_mfma(const float* __restrict__ in,
                                                    const short* __restrict__ bwt,
                                                    const float* __restrict__ bias,
                                                    float* __restrict__ out) {
    __shared__ short lds[69632];   // 136 KiB

    const int t  = threadIdx.x;    // 0..511
    const int l  = t & 63;
    const int w  = t >> 6;         // 0..7
    const int wm = w >> 2;         // 0..1  (M half: 112 rows)
    const int wn = w & 3;          // 0..3  (N quarter: 64 cols)
    const int fr = l & 15;
    const int fq = l >> 4;

    // B fragment lane offset (R8-proven): row=fr, phys chunk fq^((fr>>1)&3)
    const int laneoff = fr * 32 + ((fq ^ ((fr >> 1) & 3))) * 8;
    const int bfb = wn * 2048;     // B frag base: (wn*64)*32 shorts
    // B staging: thread t -> row t>>2, phys chunk t&3, logical kcs
    const int kcs = (t & 3) ^ ((t >> 3) & 3);

    const int bid = blockIdx.x;
    const int swz = (bid & 7) * (NBLK / 8) + (bid >> 3);   // 448 = 8*56, bijective
    const int m0  = swz * BM;

    // block geometry: one image, 4 full output rows oh0..oh0+3
    const int img = m0 / (HH * WW);
    const int oh0 = (m0 - img * (HH * WW)) / WW;

    // per-lane A fragment geometry: fragment i covers m rows m0+wm*112+i*16+fr
    int abase[7], aow[7];
#pragma unroll
    for (int i = 0; i < 7; ++i) {
        const int mm = (m0 - img * (HH * WW)) + wm * 112 + i * 16 + fr;
        const int oh = mm / WW;
        const int ow = mm - oh * WW;
        abase[i] = ((oh - oh0) * 58 + ow) * CIN;   // shorts (cell stride 128)
        aow[i]   = ow;
    }

    // B staging row bases (rows r0 and r0+128 of the 256-row B panel)
    const int r0 = t >> 2;
    const int bbase0 = r0 * KTOT;
    const int bbase1 = (r0 + 128) * KTOT;

    f32x4 acc[7][4];
#pragma unroll
    for (int i = 0; i < 7; ++i)
#pragma unroll
        for (int j = 0; j < 4; ++j) { f32x4 z = {0.f, 0.f, 0.f, 0.f}; acc[i][j] = z; }

    bf16x8 Aa[7], Ab[7], Ba[4], Bb[4];

#define STAGE_B(K, RG) do {                                                   \
        const int _kk  = (K) > 35 ? 35 : (K);                                 \
        const int _off = _kk * 32 + kcs * 8;                                  \
        short* _l = lds + B_BASE + (RG) * BREG_SZ;                            \
        async16(_l + w * 512,        bwt + bbase0 + _off);                    \
        async16(_l + 4096 + w * 512, bwt + bbase1 + _off);                    \
    } while (0)

    // A fragments for kh-phase K1 from the persistent window.
    // tap = K1>>2 (fh,fw), ch quarter q = K1&3; lane reads logical chunk
    // q*4+fq at cell (oh-oh0+fh, ow+fw); phys = logical ^ (iw&15).
#define RD_A(AF, K1) do {                                                     \
        const int _kk  = (K1) > 35 ? 35 : (K1);                               \
        const int _tap = _kk >> 2;                                            \
        const int _q   = _kk & 3;                                             \
        const int _fh  = (_tap * 11) >> 5;                                    \
        const int _fw  = _tap - 3 * _fh;                                      \
        const int _toff = (_fh * 58 + _fw) * CIN;                             \
        const int _q4 = (_q << 2) | fq;                                       \
        _Pragma("unroll")                                                     \
        for (int _i = 0; _i < 7; ++_i) {                                      \
            const int _phys = _q4 ^ ((aow[_i] + _fw) & 15);                   \
            (AF)[_i] = *(const bf16x8*)(lds + abase[_i] + _toff + (_phys << 3)); \
        }                                                                     \
    } while (0)

#define RD_B(BF, RG) do {                                                     \
        const short* _b = lds + B_BASE + (RG) * BREG_SZ + bfb;                \
        _Pragma("unroll")                                                     \
        for (int _j = 0; _j < 4; ++_j)                                        \
            (BF)[_j] = *(const bf16x8*)(_b + _j * 512 + laneoff);             \
    } while (0)

#define MM(AF, BF) do {                                                       \
        __builtin_amdgcn_s_setprio(1);                                        \
        _Pragma("unroll")                                                     \
        for (int _i = 0; _i < 7; ++_i)                                        \
            _Pragma("unroll")                                                 \
            for (int _j = 0; _j < 4; ++_j)                                    \
                acc[_i][_j] = __builtin_amdgcn_mfma_f32_16x16x32_bf16(        \
                    (AF)[_i], (BF)[_j], acc[_i][_j], 0, 0, 0);                \
        __builtin_amdgcn_s_setprio(0);                                        \
    } while (0)

    // phase: stage-B | prefetch next kh frags | 28 MFMA | VMWAIT(2) | barrier
#define PHZ(C, K, AFc, BFc, AFn, BFn) do {                                    \
        STAGE_B((K) + 3, (C) % 3);                                            \
        RD_A(AFn, (K) + 1);                                                   \
        RD_B(BFn, ((C) + 1) % 3);                                             \
        MM(AFc, BFc);                                                         \
        VMWAIT(2);                                                            \
        BARRIER();                                                            \
    } while (0)

    // ---- prologue A, pass 1: issue ALL fp32 loads into registers ----------
    // Thread handles logical chunk L = j*512+t (8 channels at one cell);
    // clamped chunks duplicate 5567 (benign).  Halo chunks skip the load
    // (exec-masked); their register values are never consumed.
    float4 fa[11], fb[11];
#pragma unroll
    for (int j = 0; j < 11; ++j) {
        const int P    = j * 512 + t;
        const int Pc   = P > (AWIN_CHUNKS - 1) ? (AWIN_CHUNKS - 1) : P;
        const int cell = Pc >> 4;
        const int lch  = Pc & 15;
        const int dr   = cell / 58;
        const int iw   = cell - dr * 58;
        const int ri   = oh0 + dr - 1;          // input row
        const int ci   = iw - 1;                // input col
        if (ri >= 0 && ri < HH && ci >= 0 && ci < WW) {
            const float* p = in + (((size_t)(img * HH + ri) * WW + ci) * CIN + lch * 8);
            fa[j] = *(const float4*)p;
            fb[j] = *(const float4*)(p + 4);
        }
    }
    // ---- prologue B: issue the 3 B-region DMAs while A-loads are in flight
    STAGE_B(0, 0); STAGE_B(1, 1); STAGE_B(2, 2);
    // ---- prologue A, pass 2: cvt + swizzled ds_write as loads retire ------
#pragma unroll
    for (int j = 0; j < 11; ++j) {
        const int P    = j * 512 + t;
        const int Pc   = P > (AWIN_CHUNKS - 1) ? (AWIN_CHUNKS - 1) : P;
        const int cell = Pc >> 4;
        const int lch  = Pc & 15;
        const int dr   = cell / 58;
        const int iw   = cell - dr * 58;
        const int ri   = oh0 + dr - 1;
        const int ci   = iw - 1;
        bf16x8 v = (bf16x8)0;
        if (ri >= 0 && ri < HH && ci >= 0 && ci < WW) {
            v.s0 = f2bf(fa[j].x); v.s1 = f2bf(fa[j].y);
            v.s2 = f2bf(fa[j].z); v.s3 = f2bf(fa[j].w);
            v.s4 = f2bf(fb[j].x); v.s5 = f2bf(fb[j].y);
            v.s6 = f2bf(fb[j].z); v.s7 = f2bf(fb[j].w);
        }
        *(bf16x8*)(lds + (cell * 16 + (lch ^ (iw & 15))) * 8) = v;
    }
    // A-loads all register-consumed above -> outstanding vm ops = 6 B DMAs.
    VMWAIT(2);                 // drains B0+B1; leaves B2 in flight
    LGKMWAIT0();               // A ds_writes visible before barrier
    BARRIER();
    RD_A(Aa, 0); RD_B(Ba, 0);
    BARRIER();

    // ---- main loop: 36 phases, 6-phase static body (B regions mod 3,
    // frag sets mod 2)
#pragma unroll 1
    for (int jb = 0; jb < NPHASE; jb += 6) {
        PHZ(0, jb + 0, Aa, Ba, Ab, Bb);
        PHZ(1, jb + 1, Ab, Bb, Aa, Ba);
        PHZ(2, jb + 2, Aa, Ba, Ab, Bb);
        PHZ(3, jb + 3, Ab, Bb, Aa, Ba);
        PHZ(4, jb + 4, Aa, Ba, Ab, Bb);
        PHZ(5, jb + 5, Ab, Bb, Aa, Ba);
    }

    VMWAIT(0);   // all DMA (incl. clamped dummies) landed before block exits

    // ---- epilogue: bias + ReLU. D: col(N)=lane&15, row(M)=fq*4+reg (m89)
#pragma unroll
    for (int j = 0; j < 4; ++j) {
        const int n  = wn * 64 + j * 16 + fr;
        const float bj = bias[n];
#pragma unroll
        for (int i = 0; i < 7; ++i) {
            const int mr = m0 + wm * 112 + i * 16 + fq * 4;
#pragma unroll
            for (int r = 0; r < 4; ++r) {
                const float v = acc[i][j][r] + bj;
                out[(size_t)(mr + r) * COUT + n] = v > 0.f ? v : 0.f;
            }
        }
    }
#undef STAGE_B
#undef RD_A
#undef RD_B
#undef MM
#undef PHZ
}

extern "C" void kernel_launch(void* const* d_in, const int* in_sizes, int n_in,
                              void* d_out, int out_size, void* d_ws, size_t ws_size,
                              hipStream_t stream) {
    const float* in   = (const float*)d_in[0];
    const float* wgt  = (const float*)d_in[1];
    const float* bias = (const float*)d_in[2];
    float* out = (float*)d_out;

    short* wt = (short*)d_ws;

    pack_wgt<<<dim3(KTOT / 32, COUT / 32), 256, 0, stream>>>(wgt, wt);
    conv_mfma<<<NBLK, 512, 0, stream>>>(in, wt, bias, out);
}